// Round 5
// baseline (394.884 us; speedup 1.0000x reference)
//
#include <hip/hip_runtime.h>
#include <stdint.h>

#define D_DIM 1024
#define T_DIM 4096
#define B_DIM 4
#define M_DIM 16384
#define NX 16777216UL
#define NW 1048576UL
#define LOG8F 2.0794415416798357f
#define CHUNK_L 64
#define NCHUNK 64
#define WARM 16

typedef __attribute__((ext_vector_type(4))) float f32x4;
typedef __attribute__((ext_vector_type(8))) short bf16x8;

__device__ __forceinline__ unsigned short f2bf(float f) {
    unsigned u = __float_as_uint(f);
    u += 0x7fffu + ((u >> 16) & 1u);
    return (unsigned short)(u >> 16);
}
__device__ __forceinline__ unsigned packbf2(float x, float y) {
    unsigned ux = __float_as_uint(x);
    ux = (ux + 0x7fffu + ((ux >> 16) & 1u)) >> 16;
    unsigned uy = __float_as_uint(y);
    uy = (uy + 0x7fffu + ((uy >> 16) & 1u)) & 0xffff0000u;
    return ux | uy;
}
__device__ __forceinline__ float unp_lo(unsigned p) { return __uint_as_float(p << 16); }
__device__ __forceinline__ float unp_hi(unsigned p) { return __uint_as_float(p & 0xffff0000u); }
__device__ __forceinline__ float sigm(float x) { return 1.0f / (1.0f + __expf(-x)); }

__device__ __forceinline__ void gl_lds16(const void* g, void* l) {
    __builtin_amdgcn_global_load_lds(
        (const __attribute__((address_space(1))) void*)g,
        (__attribute__((address_space(3))) void*)l, 16, 0, 0);
}

// ---------------------------------------------------------------------------
// Kernel 0: convert x, W_r, W_i, W_x  fp32 -> bf16 (4 elems/thread)
// ---------------------------------------------------------------------------
__global__ __launch_bounds__(256) void cvt_kernel(
    const float* __restrict__ x, const float* __restrict__ Wr,
    const float* __restrict__ Wi, const float* __restrict__ Wx,
    unsigned short* __restrict__ xb, unsigned short* __restrict__ wb)
{
    size_t tid = (size_t)blockIdx.x * 256 + threadIdx.x;
    size_t i = tid * 4;
    const float* src;
    unsigned short* dst;
    size_t off;
    if (i < NX) {
        src = x; dst = xb; off = i;
    } else {
        size_t j = i - NX;
        size_t w = j >> 20;           // / NW
        off = j & (NW - 1);
        src = (w == 0) ? Wr : (w == 1 ? Wi : Wx);
        dst = wb + w * NW;
    }
    float4 v = *(const float4*)(src + off);
    ushort4 o;
    o.x = f2bf(v.x); o.y = f2bf(v.y); o.z = f2bf(v.z); o.w = f2bf(v.w);
    *(ushort4*)(dst + off) = o;
}

// ---------------------------------------------------------------------------
// Kernel 1: fused GEMM (3 weights sequentially per 128x128 tile) + gating.
//   - R1 structure (2 blocks/CU resident — needed for wave-level overlap;
//     R4's 1-block/CU triple-fusion lost 28%)
//   - XCD swizzle (R3: FETCH 400->210 MB), identity staging (R3's staging
//     lane-permute broke the global_load_lds coalescer)
//   - BK=64: 32 MFMA per barrier-pair (vs 16) -> half the vmcnt(0)+barrier
//     drains; 32 KB LDS keeps 2 blocks/CU (m132's BK=128/64KB did not)
//   writes a (bf16) to ws, u (fp32) to d_out.
// ---------------------------------------------------------------------------
__global__ __launch_bounds__(256, 2) void fused_gemm(
    const unsigned short* __restrict__ xb, const unsigned short* __restrict__ wb,
    const float* __restrict__ b_r, const float* __restrict__ b_i,
    unsigned short* __restrict__ a_out, float* __restrict__ u_out)
{
    __shared__ __align__(16) unsigned short As[128 * 64];   // 16 KB
    __shared__ __align__(16) unsigned short Bs[128 * 64];   // 16 KB

    const int tid  = threadIdx.x;
    const int lane = tid & 63;
    const int wave = tid >> 6;
    const int wm = wave & 1;
    const int wn = wave >> 1;
    const int xcd = blockIdx.x & 7;
    const int loc = blockIdx.x >> 3;          // 0..127
    const int m0 = (xcd * 16 + (loc & 15)) * 128;
    const int d0 = (loc >> 4) * 128;
    const int frow = lane & 15;
    const int kgrp = lane >> 4;

    const int r0 = tid >> 3;            // staging row (0..31), 4 rounds of 32
    const int c0 = (tid & 7) << 3;      // k-offset within 64-k row (x8 bf16)
    const unsigned short* xrow = xb + (size_t)m0 * D_DIM;

    unsigned gip[4][4][2];              // packed bf16 persistent: gate, then gate*i

    for (int w = 0; w < 3; ++w) {
        const unsigned short* wrow = wb + (size_t)w * NW + (size_t)d0 * D_DIM;
        f32x4 acc[4][4];
        #pragma unroll
        for (int i = 0; i < 4; i++)
            #pragma unroll
            for (int j = 0; j < 4; j++) acc[i][j] = (f32x4){0.f, 0.f, 0.f, 0.f};

        for (int kk = 0; kk < 16; ++kk) {
            const int k0 = kk << 6;
            #pragma unroll
            for (int q = 0; q < 4; q++) {
                gl_lds16(xrow + (size_t)(r0 + 32 * q) * D_DIM + k0 + c0,
                         &As[(tid + 256 * q) * 8]);
                gl_lds16(wrow + (size_t)(r0 + 32 * q) * D_DIM + k0 + c0,
                         &Bs[(tid + 256 * q) * 8]);
            }
            __syncthreads();
            #pragma unroll
            for (int ks = 0; ks < 2; ks++) {
                bf16x8 af[4], bfr[4];
                #pragma unroll
                for (int i = 0; i < 4; i++)
                    af[i] = *(const bf16x8*)
                        &As[(wm * 64 + i * 16 + frow) * 64 + ks * 32 + kgrp * 8];
                #pragma unroll
                for (int j = 0; j < 4; j++)
                    bfr[j] = *(const bf16x8*)
                        &Bs[(wn * 64 + j * 16 + frow) * 64 + ks * 32 + kgrp * 8];
                #pragma unroll
                for (int i = 0; i < 4; i++)
                    #pragma unroll
                    for (int j = 0; j < 4; j++)
                        acc[i][j] = __builtin_amdgcn_mfma_f32_16x16x32_bf16(
                            af[i], bfr[j], acc[i][j], 0, 0, 0);
            }
            __syncthreads();
        }

        // Epilogue. C/D layout: col(d) = lane&15, row(m) = (lane>>4)*4 + r.
        const int mb = m0 + wm * 64;
        const int db = d0 + wn * 64;
        if (w == 0) {
            #pragma unroll
            for (int j = 0; j < 4; j++) {
                const int d = db + j * 16 + frow;
                const float br = b_r[d];
                #pragma unroll
                for (int i = 0; i < 4; i++) {
                    float g[4];
                    #pragma unroll
                    for (int r = 0; r < 4; r++) {
                        const int m = mb + i * 16 + kgrp * 4 + r;
                        float rg = sigm(acc[i][j][r] + br);
                        // exp(-softplus(z)) == sigmoid(-z);  a in (0.11, 0.5)
                        float a = sigm(-LOG8F * rg);
                        a_out[(size_t)m * D_DIM + d] = f2bf(a);
                        g[r] = sqrtf(fmaxf(1.0f - a * a, 1e-6f));
                    }
                    gip[i][j][0] = packbf2(g[0], g[1]);
                    gip[i][j][1] = packbf2(g[2], g[3]);
                }
            }
        } else if (w == 1) {
            #pragma unroll
            for (int j = 0; j < 4; j++) {
                const int d = db + j * 16 + frow;
                const float bi = b_i[d];
                #pragma unroll
                for (int i = 0; i < 4; i++) {
                    float g0 = unp_lo(gip[i][j][0]) * sigm(acc[i][j][0] + bi);
                    float g1 = unp_hi(gip[i][j][0]) * sigm(acc[i][j][1] + bi);
                    float g2 = unp_lo(gip[i][j][1]) * sigm(acc[i][j][2] + bi);
                    float g3 = unp_hi(gip[i][j][1]) * sigm(acc[i][j][3] + bi);
                    gip[i][j][0] = packbf2(g0, g1);
                    gip[i][j][1] = packbf2(g2, g3);
                }
            }
        } else {
            #pragma unroll
            for (int j = 0; j < 4; j++) {
                const int d = db + j * 16 + frow;
                #pragma unroll
                for (int i = 0; i < 4; i++) {
                    #pragma unroll
                    for (int r = 0; r < 4; r++) {
                        const int m = mb + i * 16 + kgrp * 4 + r;
                        float gi = (r & 1) ? unp_hi(gip[i][j][r >> 1])
                                           : unp_lo(gip[i][j][r >> 1]);
                        u_out[(size_t)m * D_DIM + d] = gi * acc[i][j][r];
                    }
                }
            }
        }
    }
}

// ---------------------------------------------------------------------------
// Kernel 2: chunk-start h via 16-step warm-up (a <= 0.5 => decay >= 1 bit/step,
// so truncation error <= 2^-16 * |h|). 2 d-chains per thread (float2 loads).
// Must stay a separate launch: apply overwrites u in place, warm reads u.
// ---------------------------------------------------------------------------
__global__ __launch_bounds__(256) void scan_warm(
    const unsigned short* __restrict__ a, const float* __restrict__ u,
    const float* __restrict__ h0, float* __restrict__ hstart)
{
    int tid = blockIdx.x * 256 + threadIdx.x;   // (b*NCHUNK + c)*512 + d2
    int d = (tid & 511) << 1;
    int bc = tid >> 9;
    int b = bc >> 6;
    int c = bc & (NCHUNK - 1);
    float hx, hy;
    if (c == 0) {
        float2 h = *(const float2*)(h0 + b * D_DIM + d);
        hx = h.x; hy = h.y;
    } else {
        hx = 0.0f; hy = 0.0f;
        size_t base = ((size_t)b * T_DIM + (size_t)c * CHUNK_L - WARM) * D_DIM + d;
        #pragma unroll 4
        for (int t = 0; t < WARM; t++) {
            size_t idx = base + (size_t)t * D_DIM;
            unsigned ap = *(const unsigned*)(a + idx);
            float2 uv = *(const float2*)(u + idx);
            hx = unp_lo(ap) * hx + uv.x;
            hy = unp_hi(ap) * hy + uv.y;
        }
    }
    *(float2*)(hstart + bc * D_DIM + d) = make_float2(hx, hy);
}

// ---------------------------------------------------------------------------
// Kernel 3: apply — scan each chunk from hstart, overwrite u -> h in place.
// 2 d-chains per thread. Last chunk's thread also writes h_last.
// ---------------------------------------------------------------------------
__global__ __launch_bounds__(256) void scan_apply(
    const unsigned short* __restrict__ a, const float* __restrict__ hstart,
    float* __restrict__ out)
{
    int tid = blockIdx.x * 256 + threadIdx.x;
    int d = (tid & 511) << 1;
    int bc = tid >> 9;
    int b = bc >> 6;
    int c = bc & (NCHUNK - 1);
    size_t base = ((size_t)b * T_DIM + (size_t)c * CHUNK_L) * D_DIM + d;
    float2 h = *(const float2*)(hstart + bc * D_DIM + d);
    float hx = h.x, hy = h.y;
    #pragma unroll 4
    for (int t = 0; t < CHUNK_L; t++) {
        size_t idx = base + (size_t)t * D_DIM;
        unsigned ap = *(const unsigned*)(a + idx);
        float2 uv = *(const float2*)(out + idx);
        hx = unp_lo(ap) * hx + uv.x;
        hy = unp_hi(ap) * hy + uv.y;
        *(float2*)(out + idx) = make_float2(hx, hy);
    }
    if (c == NCHUNK - 1)
        *(float2*)(out + (size_t)M_DIM * D_DIM + b * D_DIM + d) = make_float2(hx, hy);
}

// ---------------------------------------------------------------------------
extern "C" void kernel_launch(void* const* d_in, const int* in_sizes, int n_in,
                              void* d_out, int out_size, void* d_ws, size_t ws_size,
                              hipStream_t stream)
{
    const float* x  = (const float*)d_in[0];
    const float* h0 = (const float*)d_in[1];
    const float* Wr = (const float*)d_in[2];
    const float* br = (const float*)d_in[3];
    const float* Wi = (const float*)d_in[4];
    const float* bi = (const float*)d_in[5];
    const float* Wx = (const float*)d_in[6];
    float* out = (float*)d_out;

    char* ws = (char*)d_ws;
    unsigned short* xb = (unsigned short*)ws;                          // 32 MB
    unsigned short* wb = (unsigned short*)(ws + 33554432);             // 6 MB
    unsigned short* a_buf = (unsigned short*)(ws + 33554432 + 6291456);// 32 MB bf16
    float* hstart = (float*)(ws + 33554432 + 6291456 + 33554432);      // 1 MB

    // 0: fp32 -> bf16 (x and the three weights)
    cvt_kernel<<<19456, 256, 0, stream>>>(x, Wr, Wi, Wx, xb, wb);
    // 1: fused GEMM + gating. a(bf16) -> ws, u(fp32) -> d_out
    fused_gemm<<<1024, 256, 0, stream>>>(xb, wb, br, bi, a_buf, out);
    // 2: chunk-start h via warm-up (no sequential dependency)
    scan_warm<<<512, 256, 0, stream>>>(a_buf, out, h0, hstart);
    // 3: in-place chunk scan + h_last
    scan_apply<<<512, 256, 0, stream>>>(a_buf, hstart, out);
}

// Round 6
// 306.733 us; speedup vs baseline: 1.2874x; 1.2874x over previous
//
#include <hip/hip_runtime.h>
#include <stdint.h>

#define D_DIM 1024
#define T_DIM 4096
#define B_DIM 4
#define M_DIM 16384
#define NX 16777216UL
#define NW 1048576UL
#define LOG8F 2.0794415416798357f
#define CHUNK_L 64
#define NCHUNK 64
#define WARM 16

typedef __attribute__((ext_vector_type(4))) float f32x4;
typedef __attribute__((ext_vector_type(8))) short bf16x8;

__device__ __forceinline__ unsigned short f2bf(float f) {
    unsigned u = __float_as_uint(f);
    u += 0x7fffu + ((u >> 16) & 1u);
    return (unsigned short)(u >> 16);
}
__device__ __forceinline__ unsigned packbf2(float x, float y) {
    unsigned ux = __float_as_uint(x);
    ux = (ux + 0x7fffu + ((ux >> 16) & 1u)) >> 16;
    unsigned uy = __float_as_uint(y);
    uy = (uy + 0x7fffu + ((uy >> 16) & 1u)) & 0xffff0000u;
    return ux | uy;
}
__device__ __forceinline__ float unp_lo(unsigned p) { return __uint_as_float(p << 16); }
__device__ __forceinline__ float unp_hi(unsigned p) { return __uint_as_float(p & 0xffff0000u); }
__device__ __forceinline__ float sigm(float x) { return 1.0f / (1.0f + __expf(-x)); }

__device__ __forceinline__ void gl_lds16(const void* g, void* l) {
    __builtin_amdgcn_global_load_lds(
        (const __attribute__((address_space(1))) void*)g,
        (__attribute__((address_space(3))) void*)l, 16, 0, 0);
}

// ---------------------------------------------------------------------------
// Kernel 0: convert x, W_r, W_i, W_x  fp32 -> bf16 (4 elems/thread)
// ---------------------------------------------------------------------------
__global__ __launch_bounds__(256) void cvt_kernel(
    const float* __restrict__ x, const float* __restrict__ Wr,
    const float* __restrict__ Wi, const float* __restrict__ Wx,
    unsigned short* __restrict__ xb, unsigned short* __restrict__ wb)
{
    size_t tid = (size_t)blockIdx.x * 256 + threadIdx.x;
    size_t i = tid * 4;
    const float* src;
    unsigned short* dst;
    size_t off;
    if (i < NX) {
        src = x; dst = xb; off = i;
    } else {
        size_t j = i - NX;
        size_t w = j >> 20;           // / NW
        off = j & (NW - 1);
        src = (w == 0) ? Wr : (w == 1 ? Wi : Wx);
        dst = wb + w * NW;
    }
    float4 v = *(const float4*)(src + off);
    ushort4 o;
    o.x = f2bf(v.x); o.y = f2bf(v.y); o.z = f2bf(v.z); o.w = f2bf(v.w);
    *(ushort4*)(dst + off) = o;
}

// ---------------------------------------------------------------------------
// Kernel 1: 2-fused GEMM + gating.
//   Pass 1: W_r + W_i in one K-loop (acc[2][4][4] = 128 AGPR; x staged once
//           for both) -> epilogue computes a (bf16 store) and gate*i (regs).
//   Pass 2: W_x alone (R1 structure) -> epilogue writes u.
//   x staged 2x instead of 3x (the R1 GEMM is staging-traffic bound:
//   ~2450 cy/k-step vs 155 cy MFMA).
//   - natural grid map kept: bid&7 = d-tile = XCD -> per-XCD W-slice 768 KB
//     is L2-resident (R3/R5 "XCD swizzle" broke this; never a win).
//   - identity staging, BK=32 (R5's BK=64 regressed).
//   - (256,2): 128 AGPR + ~110 VGPR must stay under the 256/wave cap.
// ---------------------------------------------------------------------------
__global__ __launch_bounds__(256, 2) void fused_gemm(
    const unsigned short* __restrict__ xb, const unsigned short* __restrict__ wb,
    const float* __restrict__ b_r, const float* __restrict__ b_i,
    unsigned short* __restrict__ a_out, float* __restrict__ u_out)
{
    __shared__ __align__(16) unsigned short As[128 * 32];       //  8 KB
    __shared__ __align__(16) unsigned short Bs[2 * 128 * 32];   // 16 KB

    const int tid  = threadIdx.x;
    const int lane = tid & 63;
    const int wave = tid >> 6;
    const int wm = wave & 1;
    const int wn = wave >> 1;
    const int m0 = (blockIdx.x >> 3) * 128;
    const int d0 = (blockIdx.x & 7) * 128;
    const int frow = lane & 15;
    const int kgrp = lane >> 4;

    const int r0 = tid >> 2;            // staging row
    const int c0 = (tid & 3) << 3;      // k-offset within tile (x8 bf16)
    const unsigned short* xrow = xb + (size_t)m0 * D_DIM;
    const unsigned short* wrow = wb + (size_t)d0 * D_DIM;

    const int mb = m0 + wm * 64;
    const int db = d0 + wn * 64;

    unsigned gip[4][4][2];              // packed bf16: gate * i (pass1 -> pass2)

    // ---------------- Pass 1: W_r and W_i fused ----------------
    {
        f32x4 acc[2][4][4];
        #pragma unroll
        for (int w = 0; w < 2; w++)
            #pragma unroll
            for (int i = 0; i < 4; i++)
                #pragma unroll
                for (int j = 0; j < 4; j++) acc[w][i][j] = (f32x4){0.f, 0.f, 0.f, 0.f};

        for (int kk = 0; kk < 32; ++kk) {
            const int k0 = kk << 5;
            gl_lds16(xrow + (size_t)r0 * D_DIM + k0 + c0,        &As[tid * 8]);
            gl_lds16(xrow + (size_t)(r0 + 64) * D_DIM + k0 + c0, &As[(tid + 256) * 8]);
            #pragma unroll
            for (int w = 0; w < 2; w++) {
                gl_lds16(wrow + (size_t)w * NW + (size_t)r0 * D_DIM + k0 + c0,
                         &Bs[w * 4096 + tid * 8]);
                gl_lds16(wrow + (size_t)w * NW + (size_t)(r0 + 64) * D_DIM + k0 + c0,
                         &Bs[w * 4096 + (tid + 256) * 8]);
            }
            __syncthreads();
            bf16x8 af[4], bfr[2][4];
            #pragma unroll
            for (int i = 0; i < 4; i++)
                af[i] = *(const bf16x8*)&As[(wm * 64 + i * 16 + frow) * 32 + kgrp * 8];
            #pragma unroll
            for (int w = 0; w < 2; w++)
                #pragma unroll
                for (int j = 0; j < 4; j++)
                    bfr[w][j] = *(const bf16x8*)
                        &Bs[w * 4096 + (wn * 64 + j * 16 + frow) * 32 + kgrp * 8];
            #pragma unroll
            for (int w = 0; w < 2; w++)
                #pragma unroll
                for (int i = 0; i < 4; i++)
                    #pragma unroll
                    for (int j = 0; j < 4; j++)
                        acc[w][i][j] = __builtin_amdgcn_mfma_f32_16x16x32_bf16(
                            af[i], bfr[w][j], acc[w][i][j], 0, 0, 0);
            __syncthreads();
        }

        // Epilogue 1. C/D layout: col(d) = lane&15, row(m) = (lane>>4)*4 + r.
        #pragma unroll
        for (int j = 0; j < 4; j++) {
            const int d = db + j * 16 + frow;
            const float br = b_r[d];
            const float bi = b_i[d];
            #pragma unroll
            for (int i = 0; i < 4; i++) {
                float ig[4];
                #pragma unroll
                for (int r = 0; r < 4; r++) {
                    const int m = mb + i * 16 + kgrp * 4 + r;
                    float rg = sigm(acc[0][i][j][r] + br);
                    // exp(-softplus(z)) == sigmoid(-z);  a in (0.11, 0.5)
                    float a = sigm(-LOG8F * rg);
                    a_out[(size_t)m * D_DIM + d] = f2bf(a);
                    float g = sqrtf(fmaxf(1.0f - a * a, 1e-6f));
                    ig[r] = g * sigm(acc[1][i][j][r] + bi);
                }
                gip[i][j][0] = packbf2(ig[0], ig[1]);
                gip[i][j][1] = packbf2(ig[2], ig[3]);
            }
        }
    }

    // ---------------- Pass 2: W_x ----------------
    {
        f32x4 acc[4][4];
        #pragma unroll
        for (int i = 0; i < 4; i++)
            #pragma unroll
            for (int j = 0; j < 4; j++) acc[i][j] = (f32x4){0.f, 0.f, 0.f, 0.f};

        const unsigned short* w2 = wrow + 2 * NW;
        for (int kk = 0; kk < 32; ++kk) {
            const int k0 = kk << 5;
            gl_lds16(xrow + (size_t)r0 * D_DIM + k0 + c0,        &As[tid * 8]);
            gl_lds16(xrow + (size_t)(r0 + 64) * D_DIM + k0 + c0, &As[(tid + 256) * 8]);
            gl_lds16(w2 + (size_t)r0 * D_DIM + k0 + c0,          &Bs[tid * 8]);
            gl_lds16(w2 + (size_t)(r0 + 64) * D_DIM + k0 + c0,   &Bs[(tid + 256) * 8]);
            __syncthreads();
            bf16x8 af[4], bfr[4];
            #pragma unroll
            for (int i = 0; i < 4; i++)
                af[i] = *(const bf16x8*)&As[(wm * 64 + i * 16 + frow) * 32 + kgrp * 8];
            #pragma unroll
            for (int j = 0; j < 4; j++)
                bfr[j] = *(const bf16x8*)&Bs[(wn * 64 + j * 16 + frow) * 32 + kgrp * 8];
            #pragma unroll
            for (int i = 0; i < 4; i++)
                #pragma unroll
                for (int j = 0; j < 4; j++)
                    acc[i][j] = __builtin_amdgcn_mfma_f32_16x16x32_bf16(
                        af[i], bfr[j], acc[i][j], 0, 0, 0);
            __syncthreads();
        }

        // Epilogue 2: u = (gate * i) * (x @ W_x^T)
        #pragma unroll
        for (int j = 0; j < 4; j++) {
            const int d = db + j * 16 + frow;
            #pragma unroll
            for (int i = 0; i < 4; i++) {
                #pragma unroll
                for (int r = 0; r < 4; r++) {
                    const int m = mb + i * 16 + kgrp * 4 + r;
                    float gi = (r & 1) ? unp_hi(gip[i][j][r >> 1])
                                       : unp_lo(gip[i][j][r >> 1]);
                    u_out[(size_t)m * D_DIM + d] = gi * acc[i][j][r];
                }
            }
        }
    }
}

// ---------------------------------------------------------------------------
// Kernel 2: chunk-start h via 16-step warm-up (a <= 0.5 => decay >= 1 bit/step,
// so truncation error <= 2^-16 * |h|). 2 d-chains per thread (float2 loads).
// Must stay a separate launch: apply overwrites u in place, warm reads u.
// ---------------------------------------------------------------------------
__global__ __launch_bounds__(256) void scan_warm(
    const unsigned short* __restrict__ a, const float* __restrict__ u,
    const float* __restrict__ h0, float* __restrict__ hstart)
{
    int tid = blockIdx.x * 256 + threadIdx.x;   // (b*NCHUNK + c)*512 + d2
    int d = (tid & 511) << 1;
    int bc = tid >> 9;
    int b = bc >> 6;
    int c = bc & (NCHUNK - 1);
    float hx, hy;
    if (c == 0) {
        float2 h = *(const float2*)(h0 + b * D_DIM + d);
        hx = h.x; hy = h.y;
    } else {
        hx = 0.0f; hy = 0.0f;
        size_t base = ((size_t)b * T_DIM + (size_t)c * CHUNK_L - WARM) * D_DIM + d;
        #pragma unroll 4
        for (int t = 0; t < WARM; t++) {
            size_t idx = base + (size_t)t * D_DIM;
            unsigned ap = *(const unsigned*)(a + idx);
            float2 uv = *(const float2*)(u + idx);
            hx = unp_lo(ap) * hx + uv.x;
            hy = unp_hi(ap) * hy + uv.y;
        }
    }
    *(float2*)(hstart + bc * D_DIM + d) = make_float2(hx, hy);
}

// ---------------------------------------------------------------------------
// Kernel 3: apply — scan each chunk from hstart, overwrite u -> h in place.
// 2 d-chains per thread. Last chunk's thread also writes h_last.
// ---------------------------------------------------------------------------
__global__ __launch_bounds__(256) void scan_apply(
    const unsigned short* __restrict__ a, const float* __restrict__ hstart,
    float* __restrict__ out)
{
    int tid = blockIdx.x * 256 + threadIdx.x;
    int d = (tid & 511) << 1;
    int bc = tid >> 9;
    int b = bc >> 6;
    int c = bc & (NCHUNK - 1);
    size_t base = ((size_t)b * T_DIM + (size_t)c * CHUNK_L) * D_DIM + d;
    float2 h = *(const float2*)(hstart + bc * D_DIM + d);
    float hx = h.x, hy = h.y;
    #pragma unroll 4
    for (int t = 0; t < CHUNK_L; t++) {
        size_t idx = base + (size_t)t * D_DIM;
        unsigned ap = *(const unsigned*)(a + idx);
        float2 uv = *(const float2*)(out + idx);
        hx = unp_lo(ap) * hx + uv.x;
        hy = unp_hi(ap) * hy + uv.y;
        *(float2*)(out + idx) = make_float2(hx, hy);
    }
    if (c == NCHUNK - 1)
        *(float2*)(out + (size_t)M_DIM * D_DIM + b * D_DIM + d) = make_float2(hx, hy);
}

// ---------------------------------------------------------------------------
extern "C" void kernel_launch(void* const* d_in, const int* in_sizes, int n_in,
                              void* d_out, int out_size, void* d_ws, size_t ws_size,
                              hipStream_t stream)
{
    const float* x  = (const float*)d_in[0];
    const float* h0 = (const float*)d_in[1];
    const float* Wr = (const float*)d_in[2];
    const float* br = (const float*)d_in[3];
    const float* Wi = (const float*)d_in[4];
    const float* bi = (const float*)d_in[5];
    const float* Wx = (const float*)d_in[6];
    float* out = (float*)d_out;

    char* ws = (char*)d_ws;
    unsigned short* xb = (unsigned short*)ws;                          // 32 MB
    unsigned short* wb = (unsigned short*)(ws + 33554432);             // 6 MB
    unsigned short* a_buf = (unsigned short*)(ws + 33554432 + 6291456);// 32 MB bf16
    float* hstart = (float*)(ws + 33554432 + 6291456 + 33554432);      // 1 MB

    // 0: fp32 -> bf16 (x and the three weights)
    cvt_kernel<<<19456, 256, 0, stream>>>(x, Wr, Wi, Wx, xb, wb);
    // 1: 2-fused GEMM + gating. a(bf16) -> ws, u(fp32) -> d_out
    fused_gemm<<<1024, 256, 0, stream>>>(xb, wb, br, bi, a_buf, out);
    // 2: chunk-start h via warm-up (no sequential dependency)
    scan_warm<<<512, 256, 0, stream>>>(a_buf, out, h0, hstart);
    // 3: in-place chunk scan + h_last
    scan_apply<<<512, 256, 0, stream>>>(a_buf, hstart, out);
}